// Round 1
// baseline (892.828 us; speedup 1.0000x reference)
//
#include <hip/hip_runtime.h>

#define NN 100000
#define NE 1600000
#define F  128

constexpr float EPS   = 1e-5f;
constexpr float SLOPE = 0.01f;

// ---------------- kernel 1: init deg=1 (self loop), zero stats ----------------
__global__ void k_init(float* __restrict__ deg, float* __restrict__ stats) {
    int i = blockIdx.x * blockDim.x + threadIdx.x;
    if (i < NN) deg[i] = 1.0f;
    if (i < 2 * F) stats[i] = 0.0f;   // sums[128] + sumsq[128]
}

// ---------------- kernel 2: in-degree count over dst ----------------
__global__ void k_deg(const int* __restrict__ dst, float* __restrict__ deg) {
    int i = blockIdx.x * blockDim.x + threadIdx.x;
    if (i < NE) atomicAdd(&deg[dst[i]], 1.0f);
}

// ---------------- kernel 3: dis = rsqrt(deg) ----------------
__global__ void k_dis(const float* __restrict__ deg, float* __restrict__ dis) {
    int i = blockIdx.x * blockDim.x + threadIdx.x;
    if (i < NN) dis[i] = rsqrtf(deg[i]);  // deg >= 1 always (self loop)
}

// ---------------- kernel 4: h = x @ W (fp32, 16 rows/block) ----------------
#define GR 16
__global__ __launch_bounds__(256) void k_gemm(const float* __restrict__ x,
                                              const float* __restrict__ Wm,
                                              float* __restrict__ hout) {
    __shared__ float xs[GR][F];
    const int tx = threadIdx.x & 127;       // feature
    const int ty = threadIdx.x >> 7;        // 0/1
    const long base = (long)blockIdx.x * GR;

    // cooperative load: 16 rows x 128 floats by 256 threads
    for (int r = ty; r < GR; r += 2) {
        xs[r][tx] = x[(base + r) * F + tx];
    }
    __syncthreads();

    float acc[GR / 2];
#pragma unroll
    for (int r = 0; r < GR / 2; ++r) acc[r] = 0.0f;

    for (int k = 0; k < F; ++k) {
        float w = Wm[(long)k * F + tx];
#pragma unroll
        for (int r = 0; r < GR / 2; ++r) {
            acc[r] += xs[ty * (GR / 2) + r][k] * w;   // LDS broadcast per wave
        }
    }
#pragma unroll
    for (int r = 0; r < GR / 2; ++r) {
        hout[(base + ty * (GR / 2) + r) * F + tx] = acc[r];
    }
}

// ---------------- kernel 5: agg = b + h * dis^2 (self loop), into d_out ----------------
__global__ void k_selfinit(const float* __restrict__ h, const float* __restrict__ dis,
                           const float* __restrict__ b, float* __restrict__ agg) {
    const long total = (long)NN * F;
    for (long i = (long)blockIdx.x * blockDim.x + threadIdx.x; i < total;
         i += (long)gridDim.x * blockDim.x) {
        int node = (int)(i >> 7);
        int f = (int)(i & 127);
        float d = dis[node];
        agg[i] = b[f] + h[i] * d * d;
    }
}

// ---------------- kernel 6: edge scatter with atomics ----------------
__global__ __launch_bounds__(256) void k_scatter(const int* __restrict__ ei,
                                                 const float* __restrict__ h,
                                                 const float* __restrict__ dis,
                                                 float* __restrict__ agg) {
    const int tx = threadIdx.x & 127;
    const int slot = (blockIdx.x << 1) + (threadIdx.x >> 7);
    const int stride = gridDim.x << 1;
    for (int e = slot; e < NE; e += stride) {
        int s = ei[e];
        int d = ei[NE + e];
        float nrm = dis[s] * dis[d];
        atomicAdd(&agg[(long)d * F + tx], h[(long)s * F + tx] * nrm);
    }
}

// ---------------- kernel 7: per-feature sums / sumsq ----------------
__global__ __launch_bounds__(256) void k_stats(const float* __restrict__ agg,
                                               float* __restrict__ sums,
                                               float* __restrict__ sumsq) {
    __shared__ float red[2][F];
    const int tx = threadIdx.x & 127;
    const int ty = threadIdx.x >> 7;
    float s = 0.0f, s2 = 0.0f;
    for (int row = blockIdx.x * 2 + ty; row < NN; row += gridDim.x * 2) {
        float v = agg[(long)row * F + tx];
        s += v;
        s2 += v * v;
    }
    red[ty][tx] = s;
    __syncthreads();
    if (ty == 0) atomicAdd(&sums[tx], s + red[1][tx]);
    __syncthreads();
    red[ty][tx] = s2;
    __syncthreads();
    if (ty == 0) atomicAdd(&sumsq[tx], s2 + red[1][tx]);
}

// ---------------- kernel 8: finalize stats -> per-feature affine ----------------
__global__ void k_finstats(const float* __restrict__ sums, const float* __restrict__ sumsq,
                           const float* __restrict__ gw, const float* __restrict__ gb,
                           const float* __restrict__ gms,
                           float* __restrict__ A, float* __restrict__ Bc) {
    int f = threadIdx.x;
    if (f < F) {
        const float invn = 1.0f / (float)NN;
        float mean = sums[f] * invn;
        float ms = mean * gms[f];
        float var = sumsq[f] * invn - 2.0f * ms * mean + ms * ms;
        float inv = rsqrtf(var + EPS);
        float a = inv * gw[f];
        A[f] = a;
        Bc[f] = gb[f] - ms * a;
    }
}

// ---------------- kernel 9: in-place GraphNorm affine + LeakyReLU ----------------
__global__ void k_final(float* __restrict__ out, const float* __restrict__ A,
                        const float* __restrict__ Bc) {
    const long total = (long)NN * F;
    for (long i = (long)blockIdx.x * blockDim.x + threadIdx.x; i < total;
         i += (long)gridDim.x * blockDim.x) {
        int f = (int)(i & 127);
        float v = out[i] * A[f] + Bc[f];
        out[i] = v > 0.0f ? v : SLOPE * v;
    }
}

// ---------------- kernel 10: edge_index passthrough as float ----------------
__global__ void k_eicopy(const int* __restrict__ ei, float* __restrict__ out1) {
    const long total = 2L * NE;
    for (long i = (long)blockIdx.x * blockDim.x + threadIdx.x; i < total;
         i += (long)gridDim.x * blockDim.x) {
        out1[i] = (float)ei[i];
    }
}

extern "C" void kernel_launch(void* const* d_in, const int* in_sizes, int n_in,
                              void* d_out, int out_size, void* d_ws, size_t ws_size,
                              hipStream_t stream) {
    const float* x   = (const float*)d_in[0];
    const int*   ei  = (const int*)d_in[1];
    const float* Wm  = (const float*)d_in[2];
    const float* b   = (const float*)d_in[3];
    const float* gw  = (const float*)d_in[4];
    const float* gb  = (const float*)d_in[5];
    const float* gms = (const float*)d_in[6];

    float* out  = (float*)d_out;            // region0: NN*F, region1: 2*NE
    float* out1 = out + (size_t)NN * F;

    float* ws    = (float*)d_ws;
    float* h     = ws;                       // NN*F floats
    float* deg   = ws + (size_t)NN * F;      // NN
    float* dis   = deg + NN;                 // NN
    float* stats = dis + NN;                 // sums[F], sumsq[F], A[F], Bc[F]
    float* sums  = stats;
    float* sumsq = stats + F;
    float* A     = stats + 2 * F;
    float* Bc    = stats + 3 * F;

    k_init<<<(NN + 255) / 256, 256, 0, stream>>>(deg, stats);
    k_deg<<<(NE + 255) / 256, 256, 0, stream>>>(ei + NE, deg);
    k_dis<<<(NN + 255) / 256, 256, 0, stream>>>(deg, dis);
    k_gemm<<<NN / GR, 256, 0, stream>>>(x, Wm, h);                 // 100000/16 = 6250
    k_selfinit<<<2048, 256, 0, stream>>>(h, dis, b, out);
    k_scatter<<<51200, 256, 0, stream>>>(ei, h, dis, out);
    k_stats<<<1024, 256, 0, stream>>>(out, sums, sumsq);
    k_finstats<<<1, F, 0, stream>>>(sums, sumsq, gw, gb, gms, A, Bc);
    k_final<<<2048, 256, 0, stream>>>(out, A, Bc);
    k_eicopy<<<2048, 256, 0, stream>>>(ei, out1);
}

// Round 2
// 447.028 us; speedup vs baseline: 1.9973x; 1.9973x over previous
//
#include <hip/hip_runtime.h>

#define NN 100000
#define NE 1600000
#define F  128
#define NB 391          // ceil(NN/256) blocks for scan

constexpr float EPS   = 1e-5f;
constexpr float SLOPE = 0.01f;

// ---------------- kernel 1: zero deg_i, cursor, stats ----------------
__global__ void k_init(unsigned int* __restrict__ deg_i, unsigned int* __restrict__ cursor,
                       float* __restrict__ stats) {
    int i = blockIdx.x * blockDim.x + threadIdx.x;
    if (i < NN) { deg_i[i] = 0u; cursor[i] = 0u; }
    if (i < 2 * F) stats[i] = 0.0f;   // sums[128] + sumsq[128]
}

// ---------------- kernel 2: in-degree count over dst ----------------
__global__ void k_deg(const int* __restrict__ dst, unsigned int* __restrict__ deg_i) {
    int i = blockIdx.x * blockDim.x + threadIdx.x;
    if (i < NE) atomicAdd(&deg_i[dst[i]], 1u);
}

// ---------------- kernel 3: dis = rsqrt(deg+1)  (+1 = self loop) ----------------
__global__ void k_dis(const unsigned int* __restrict__ deg_i, float* __restrict__ dis) {
    int i = blockIdx.x * blockDim.x + threadIdx.x;
    if (i < NN) dis[i] = rsqrtf((float)(deg_i[i] + 1u));
}

// ---------------- prefix scan (3 kernels) -> row_start ----------------
__global__ void k_scanA(const unsigned int* __restrict__ deg_i, unsigned int* __restrict__ scan,
                        unsigned int* __restrict__ bsums) {
    __shared__ unsigned int s[256];
    const int t = threadIdx.x;
    const int i = blockIdx.x * 256 + t;
    unsigned int v = (i < NN) ? deg_i[i] : 0u;
    s[t] = v;
    __syncthreads();
    for (int off = 1; off < 256; off <<= 1) {
        unsigned int a = (t >= off) ? s[t - off] : 0u;
        __syncthreads();
        s[t] += a;
        __syncthreads();
    }
    if (i < NN) scan[i] = s[t];
    if (t == 255) bsums[blockIdx.x] = s[255];
}

__global__ void k_scanB(const unsigned int* __restrict__ bsums, unsigned int* __restrict__ boff) {
    __shared__ unsigned int s[512];
    const int t = threadIdx.x;
    unsigned int v = (t < NB) ? bsums[t] : 0u;
    s[t] = v;
    __syncthreads();
    for (int off = 1; off < 512; off <<= 1) {
        unsigned int a = (t >= off) ? s[t - off] : 0u;
        __syncthreads();
        s[t] += a;
        __syncthreads();
    }
    if (t < NB) boff[t] = s[t] - v;   // exclusive prefix of block sums
}

__global__ void k_scanC(const unsigned int* __restrict__ scan, const unsigned int* __restrict__ boff,
                        int* __restrict__ row_start) {
    int i = blockIdx.x * 256 + threadIdx.x;
    if (i < NN) row_start[i + 1] = (int)(scan[i] + boff[i >> 8]);
    if (i == 0) row_start[0] = 0;
}

// ---------------- kernel: fill CSR (counting sort by dst) ----------------
__global__ void k_fill(const int* __restrict__ ei, const int* __restrict__ row_start,
                       unsigned int* __restrict__ cursor, int* __restrict__ csr) {
    int e = blockIdx.x * 256 + threadIdx.x;
    if (e < NE) {
        int s = ei[e], d = ei[NE + e];
        unsigned int pos = atomicAdd(&cursor[d], 1u);
        csr[row_start[d] + (int)pos] = s;
    }
}

// ---------------- GEMM: g = (x @ W) * dis, packed bf16 pairs ----------------
#define GR 16
__global__ __launch_bounds__(256) void k_gemm(const float* __restrict__ x,
                                              const float* __restrict__ Wm,
                                              const float* __restrict__ dis,
                                              unsigned int* __restrict__ g) {
    __shared__ float xs[GR][F];
    const int tx = threadIdx.x & 63;    // feature-pair index (features 2tx, 2tx+1)
    const int ty = threadIdx.x >> 6;    // 0..3 row group
    const long base = (long)blockIdx.x * GR;

    for (int r = ty; r < GR; r += 4) {
        xs[r][tx]      = x[(base + r) * F + tx];
        xs[r][tx + 64] = x[(base + r) * F + tx + 64];
    }
    __syncthreads();

    float acc[4][2] = {{0.f,0.f},{0.f,0.f},{0.f,0.f},{0.f,0.f}};
    for (int k = 0; k < F; ++k) {
        float2 w = *(const float2*)&Wm[(long)k * F + 2 * tx];
#pragma unroll
        for (int r = 0; r < 4; ++r) {
            float xv = xs[ty * 4 + r][k];
            acc[r][0] += xv * w.x;
            acc[r][1] += xv * w.y;
        }
    }
#pragma unroll
    for (int r = 0; r < 4; ++r) {
        long row = base + ty * 4 + r;
        float d = dis[row];
        unsigned int u0 = __float_as_uint(acc[r][0] * d);
        unsigned int u1 = __float_as_uint(acc[r][1] * d);
        u0 = (u0 + 0x7fffu + ((u0 >> 16) & 1u)) >> 16;                 // RNE bf16, low half
        u1 = (u1 + 0x7fffu + ((u1 >> 16) & 1u)) & 0xffff0000u;         // RNE bf16, high half
        g[row * 64 + tx] = u0 | u1;
    }
}

// ---------------- gather: out = b + dis[n]*(g[n] + sum g[src]) ----------------
__global__ __launch_bounds__(256) void k_gather(const unsigned int* __restrict__ g,
                                                const int* __restrict__ csr,
                                                const int* __restrict__ row_start,
                                                const float* __restrict__ dis,
                                                const float* __restrict__ b,
                                                float* __restrict__ out) {
    const int lane = threadIdx.x & 63;
    const int node = blockIdx.x * 4 + (threadIdx.x >> 6);
    if (node >= NN) return;

    unsigned int u = g[(long)node * 64 + lane];
    float acc0 = __uint_as_float(u << 16);
    float acc1 = __uint_as_float(u & 0xffff0000u);

    int j = row_start[node];
    const int e = row_start[node + 1];
    for (; j + 1 < e; j += 2) {
        int s0 = csr[j], s1 = csr[j + 1];
        unsigned int v0 = g[(long)s0 * 64 + lane];
        unsigned int v1 = g[(long)s1 * 64 + lane];
        acc0 += __uint_as_float(v0 << 16);
        acc1 += __uint_as_float(v0 & 0xffff0000u);
        acc0 += __uint_as_float(v1 << 16);
        acc1 += __uint_as_float(v1 & 0xffff0000u);
    }
    if (j < e) {
        int s = csr[j];
        unsigned int v = g[(long)s * 64 + lane];
        acc0 += __uint_as_float(v << 16);
        acc1 += __uint_as_float(v & 0xffff0000u);
    }
    float d = dis[node];
    float2 r;
    r.x = b[lane * 2]     + d * acc0;
    r.y = b[lane * 2 + 1] + d * acc1;
    *(float2*)&out[(long)node * F + lane * 2] = r;
}

// ---------------- per-feature sums / sumsq ----------------
__global__ __launch_bounds__(256) void k_stats(const float* __restrict__ agg,
                                               float* __restrict__ sums,
                                               float* __restrict__ sumsq) {
    __shared__ float red[2][F];
    const int tx = threadIdx.x & 127;
    const int ty = threadIdx.x >> 7;
    float s = 0.0f, s2 = 0.0f;
    for (int row = blockIdx.x * 2 + ty; row < NN; row += gridDim.x * 2) {
        float v = agg[(long)row * F + tx];
        s += v;
        s2 += v * v;
    }
    red[ty][tx] = s;
    __syncthreads();
    if (ty == 0) atomicAdd(&sums[tx], s + red[1][tx]);
    __syncthreads();
    red[ty][tx] = s2;
    __syncthreads();
    if (ty == 0) atomicAdd(&sumsq[tx], s2 + red[1][tx]);
}

// ---------------- finalize stats -> per-feature affine ----------------
__global__ void k_finstats(const float* __restrict__ sums, const float* __restrict__ sumsq,
                           const float* __restrict__ gw, const float* __restrict__ gb,
                           const float* __restrict__ gms,
                           float* __restrict__ A, float* __restrict__ Bc) {
    int f = threadIdx.x;
    if (f < F) {
        const float invn = 1.0f / (float)NN;
        float mean = sums[f] * invn;
        float ms = mean * gms[f];
        float var = sumsq[f] * invn - 2.0f * ms * mean + ms * ms;
        float inv = rsqrtf(var + EPS);
        float a = inv * gw[f];
        A[f] = a;
        Bc[f] = gb[f] - ms * a;
    }
}

// ---------------- in-place GraphNorm affine + LeakyReLU ----------------
__global__ void k_final(float* __restrict__ out, const float* __restrict__ A,
                        const float* __restrict__ Bc) {
    const long total = (long)NN * F;
    for (long i = (long)blockIdx.x * blockDim.x + threadIdx.x; i < total;
         i += (long)gridDim.x * blockDim.x) {
        int f = (int)(i & 127);
        float v = out[i] * A[f] + Bc[f];
        out[i] = v > 0.0f ? v : SLOPE * v;
    }
}

// ---------------- edge_index passthrough as float ----------------
__global__ void k_eicopy(const int* __restrict__ ei, float* __restrict__ out1) {
    const long total = 2L * NE;
    for (long i = (long)blockIdx.x * blockDim.x + threadIdx.x; i < total;
         i += (long)gridDim.x * blockDim.x) {
        out1[i] = (float)ei[i];
    }
}

extern "C" void kernel_launch(void* const* d_in, const int* in_sizes, int n_in,
                              void* d_out, int out_size, void* d_ws, size_t ws_size,
                              hipStream_t stream) {
    const float* x   = (const float*)d_in[0];
    const int*   ei  = (const int*)d_in[1];
    const float* Wm  = (const float*)d_in[2];
    const float* b   = (const float*)d_in[3];
    const float* gw  = (const float*)d_in[4];
    const float* gb  = (const float*)d_in[5];
    const float* gms = (const float*)d_in[6];

    float* out  = (float*)d_out;            // region0: NN*F, region1: 2*NE
    float* out1 = out + (size_t)NN * F;

    // ws layout (4-byte units)
    unsigned int* wsu   = (unsigned int*)d_ws;
    unsigned int* g     = wsu;                         // NN*64
    unsigned int* deg_i = g + (size_t)NN * 64;         // NN
    unsigned int* scan  = deg_i + NN;                  // NN
    unsigned int* bsums = scan + NN;                   // 512
    unsigned int* boff  = bsums + 512;                 // 512
    unsigned int* cursor= boff + 512;                  // NN
    int* row_start      = (int*)(cursor + NN);         // NN+1
    int* csr            = row_start + NN + 2;          // NE
    float* dis          = (float*)(csr + NE);          // NN
    float* stats        = dis + NN;                    // 512
    float* sums  = stats;
    float* sumsq = stats + F;
    float* A     = stats + 2 * F;
    float* Bc    = stats + 3 * F;

    k_init<<<(NN + 255) / 256, 256, 0, stream>>>(deg_i, cursor, stats);
    k_deg<<<(NE + 255) / 256, 256, 0, stream>>>(ei + NE, deg_i);
    k_dis<<<(NN + 255) / 256, 256, 0, stream>>>(deg_i, dis);
    k_scanA<<<NB, 256, 0, stream>>>(deg_i, scan, bsums);
    k_scanB<<<1, 512, 0, stream>>>(bsums, boff);
    k_scanC<<<NB, 256, 0, stream>>>(scan, boff, row_start);
    k_fill<<<(NE + 255) / 256, 256, 0, stream>>>(ei, row_start, cursor, csr);
    k_gemm<<<NN / GR, 256, 0, stream>>>(x, Wm, dis, g);
    k_gather<<<(NN + 3) / 4, 256, 0, stream>>>(g, csr, row_start, dis, b, out);
    k_stats<<<1024, 256, 0, stream>>>(out, sums, sumsq);
    k_finstats<<<1, F, 0, stream>>>(sums, sumsq, gw, gb, gms, A, Bc);
    k_final<<<2048, 256, 0, stream>>>(out, A, Bc);
    k_eicopy<<<2048, 256, 0, stream>>>(ei, out1);
}